// Round 1
// baseline (268.231 us; speedup 1.0000x reference)
//
#include <hip/hip_runtime.h>
#include <math.h>

#define BEAMS 16
#define TMAX  2048
#define HH    32
#define DD    128

// ---------------------------------------------------------------------------
// Kernel 1: beam back-trace via chunked suffix composition scan.
// trace[t] = beam_idx[t] o trace[t+1],  trace[offset] = identity
// => trace[t] = beam_idx[t] o beam_idx[t+1] o ... o beam_idx[offset-1]
// Output transposed: trace_T[b][t] (contiguous per beam for the attn kernel).
// ---------------------------------------------------------------------------
__global__ __launch_bounds__(1024)
void trace_kernel(const int* __restrict__ beam_idx,
                  const int* __restrict__ offp,
                  int* __restrict__ trace_T) {
    const int off = *offp;                 // history length (2047)
    const int C   = 16;                    // chunk size
    const int NC  = (off + C - 1) / C;     // #chunks over [0, off), <= 128

    __shared__ int S[2][128][BEAMS];

    const int tid = threadIdx.x;
    const int g   = tid >> 4;              // 64 groups
    const int j   = tid & 15;              // lane-in-group = beam

    // Phase A: per-chunk composed map into S[0]
    for (int c = g; c < NC; c += 64) {
        int cur = j;
        const int t_hi = min((c + 1) * C, off);
        for (int t = t_hi - 1; t >= c * C; --t)
            cur = beam_idx[t * BEAMS + cur];
        S[0][c][j] = cur;
    }
    __syncthreads();

    // Phase B: suffix composition by doubling:
    //   S_new[c] = S_old[c] o S_old[c+step]   (identity past the end)
    int rb = 0;
    for (int step = 1; step < NC; step <<= 1) {
        const int wb = rb ^ 1;
        for (int c = g; c < NC; c += 64) {
            int v;
            if (c + step < NC) v = S[rb][c][ S[rb][c + step][j] ];
            else               v = S[rb][c][j];
            S[wb][c][j] = v;
        }
        __syncthreads();
        rb = wb;
    }

    // Phase C: re-walk each chunk seeded with the suffix of the NEXT chunk.
    for (int c = g; c < NC; c += 64) {
        int cur = (c + 1 < NC) ? S[rb][c + 1][j] : j;
        const int t_hi = min((c + 1) * C, off);
        for (int t = t_hi - 1; t >= c * C; --t) {
            cur = beam_idx[t * BEAMS + cur];
            trace_T[j * TMAX + t] = cur;
        }
    }
}

// ---------------------------------------------------------------------------
// Kernel 2: gathered decode attention, one block per (b,h).
// 256 threads = 4 waves; each wave handles 2 t-rows per iteration
// (32 lanes x float4 = one 128-float K/V row, coalesced 512B).
// Scores staged in LDS -> exact softmax, K and V each read once.
// ---------------------------------------------------------------------------
__global__ __launch_bounds__(256)
void attn_kernel(const float* __restrict__ q,
                 const float* __restrict__ knew,
                 const float* __restrict__ vnew,
                 const float* __restrict__ kc,
                 const float* __restrict__ vc,
                 const float* __restrict__ mask,
                 const int*   __restrict__ trace_T,
                 const int*   __restrict__ offp,
                 float* __restrict__ out) {
    const int off = *offp;
    const int T   = off + 1;
    const int bh  = blockIdx.x;
    const int b   = bh >> 5;               // /H (=32)
    const int h   = bh & 31;

    __shared__ float sc[TMAX];
    __shared__ float red[8];
    __shared__ float oacc[4][DD];

    const int tid  = threadIdx.x;
    const int wave = tid >> 6;             // 0..3
    const int sub  = (tid >> 5) & 1;       // row within wave pair
    const int l32  = tid & 31;
    const int d0   = l32 * 4;

    const float inv_scale = 0.08838834764831843f;  // 1/sqrt(128)

    const float* qp = q + (size_t)(b * HH + h) * DD;
    const float4 qf = *(const float4*)(qp + d0);
    const int* tr = trace_T + b * TMAX;

    // ---- pass 1: scores ----
    float m_local = -3.4e38f;
    for (int t = wave * 2 + sub; t < T; t += 8) {
        const float* kp;
        if (t < off) {
            const int beam = tr[t];
            kp = kc + ((size_t)(t * BEAMS + beam) * HH + h) * DD;
        } else {
            kp = knew + (size_t)(b * HH + h) * DD;
        }
        const float4 kf = *(const float4*)(kp + d0);
        float s = qf.x * kf.x + qf.y * kf.y + qf.z * kf.z + qf.w * kf.w;
        #pragma unroll
        for (int o = 16; o > 0; o >>= 1) s += __shfl_xor(s, o, 32);
        s = s * inv_scale + mask[b * T + t];
        if (l32 == 0) sc[t] = s;
        m_local = fmaxf(m_local, s);
    }
    // block max
    m_local = fmaxf(m_local, __shfl_xor(m_local, 32, 64));
    if ((tid & 63) == 0) red[wave] = m_local;
    __syncthreads();
    const float m = fmaxf(fmaxf(red[0], red[1]), fmaxf(red[2], red[3]));

    // ---- pass 2: exp + sum ----
    float sum_local = 0.f;
    for (int t = tid; t < T; t += 256) {
        const float p = __expf(sc[t] - m);
        sc[t] = p;
        sum_local += p;
    }
    #pragma unroll
    for (int o = 32; o > 0; o >>= 1) sum_local += __shfl_xor(sum_local, o, 64);
    if ((tid & 63) == 0) red[4 + wave] = sum_local;
    __syncthreads();
    const float inv_sum = 1.f / (red[4] + red[5] + red[6] + red[7]);

    // ---- pass 3: p * V ----
    float ax = 0.f, ay = 0.f, az = 0.f, aw = 0.f;
    for (int t = wave * 2 + sub; t < T; t += 8) {
        const float p = sc[t];
        const float* vp;
        if (t < off) {
            const int beam = tr[t];
            vp = vc + ((size_t)(t * BEAMS + beam) * HH + h) * DD;
        } else {
            vp = vnew + (size_t)(b * HH + h) * DD;
        }
        const float4 vf = *(const float4*)(vp + d0);
        ax += p * vf.x; ay += p * vf.y; az += p * vf.z; aw += p * vf.w;
    }
    ax += __shfl_xor(ax, 32, 64);
    ay += __shfl_xor(ay, 32, 64);
    az += __shfl_xor(az, 32, 64);
    aw += __shfl_xor(aw, 32, 64);
    if (sub == 0) {
        oacc[wave][d0 + 0] = ax;
        oacc[wave][d0 + 1] = ay;
        oacc[wave][d0 + 2] = az;
        oacc[wave][d0 + 3] = aw;
    }
    __syncthreads();
    if (tid < DD) {
        const float o = (oacc[0][tid] + oacc[1][tid] + oacc[2][tid] + oacc[3][tid]) * inv_sum;
        out[(size_t)(b * HH + h) * DD + tid] = o;
    }
}

// ---------------------------------------------------------------------------
extern "C" void kernel_launch(void* const* d_in, const int* in_sizes, int n_in,
                              void* d_out, int out_size, void* d_ws, size_t ws_size,
                              hipStream_t stream) {
    const float* q    = (const float*)d_in[0];
    const float* knew = (const float*)d_in[1];
    const float* vnew = (const float*)d_in[2];
    const float* kc   = (const float*)d_in[3];
    const float* vc   = (const float*)d_in[4];
    const int*   bidx = (const int*)d_in[5];
    const float* mask = (const float*)d_in[6];
    const int*   offp = (const int*)d_in[7];

    int* trace_T = (int*)d_ws;   // BEAMS * TMAX ints = 128 KiB

    hipLaunchKernelGGL(trace_kernel, dim3(1), dim3(1024), 0, stream,
                       bidx, offp, trace_T);
    hipLaunchKernelGGL(attn_kernel, dim3(BEAMS * HH), dim3(256), 0, stream,
                       q, knew, vnew, kc, vc, mask, trace_T, offp,
                       (float*)d_out);
}

// Round 2
// 91.201 us; speedup vs baseline: 2.9411x; 2.9411x over previous
//
#include <hip/hip_runtime.h>
#include <math.h>

#define BEAMS  16
#define TMAX   2048
#define HH     32
#define DD     128
#define NSPLIT 8
#define TS_MAX 256   // ceil(TMAX / NSPLIT)

// ---------------------------------------------------------------------------
// Kernel 1: beam back-trace via chunked suffix composition scan.
// trace[t] = beam_idx[t] o trace[t+1]; output transposed trace_T[b][t].
// Phases A/C interleave two independent gather chains per group for 2x MLP.
// ---------------------------------------------------------------------------
__global__ __launch_bounds__(1024)
void trace_kernel(const int* __restrict__ beam_idx,
                  const int* __restrict__ offp,
                  int* __restrict__ trace_T) {
    const int off = *offp;
    const int C   = 16;
    const int NC  = (off + C - 1) / C;     // <= 128

    __shared__ int S[2][128][BEAMS];

    const int tid = threadIdx.x;
    const int g   = tid >> 4;              // 64 groups
    const int j   = tid & 15;              // beam lane

    // Phase A: per-chunk composed maps (chunks g and g+64 interleaved)
    {
        const int c0 = g, c1 = g + 64;
        int cur0 = j, cur1 = j;
        const int hi0 = (c0 < NC) ? min((c0 + 1) * C, off) : 0;
        const int hi1 = (c1 < NC) ? min((c1 + 1) * C, off) : 0;
        const int lo0 = c0 * C, lo1 = c1 * C;
        for (int i = 0; i < C; ++i) {
            const int ta = hi0 - 1 - i;
            if (c0 < NC && ta >= lo0) cur0 = beam_idx[ta * BEAMS + cur0];
            const int tb = hi1 - 1 - i;
            if (c1 < NC && tb >= lo1) cur1 = beam_idx[tb * BEAMS + cur1];
        }
        if (c0 < NC) S[0][c0][j] = cur0;
        if (c1 < NC) S[0][c1][j] = cur1;
    }
    __syncthreads();

    // Phase B: suffix composition by doubling
    int rb = 0;
    for (int step = 1; step < NC; step <<= 1) {
        const int wb = rb ^ 1;
        for (int c = g; c < NC; c += 64) {
            int v;
            if (c + step < NC) v = S[rb][c][ S[rb][c + step][j] ];
            else               v = S[rb][c][j];
            S[wb][c][j] = v;
        }
        __syncthreads();
        rb = wb;
    }

    // Phase C: re-walk chunks seeded with the next chunk's suffix map
    {
        const int c0 = g, c1 = g + 64;
        int cur0 = (c0 + 1 < NC) ? S[rb][c0 + 1][j] : j;
        int cur1 = (c1 + 1 < NC) ? S[rb][c1 + 1][j] : j;
        const int hi0 = (c0 < NC) ? min((c0 + 1) * C, off) : 0;
        const int hi1 = (c1 < NC) ? min((c1 + 1) * C, off) : 0;
        const int lo0 = c0 * C, lo1 = c1 * C;
        for (int i = 0; i < C; ++i) {
            const int ta = hi0 - 1 - i;
            if (c0 < NC && ta >= lo0) {
                cur0 = beam_idx[ta * BEAMS + cur0];
                trace_T[j * TMAX + ta] = cur0;
            }
            const int tb = hi1 - 1 - i;
            if (c1 < NC && tb >= lo1) {
                cur1 = beam_idx[tb * BEAMS + cur1];
                trace_T[j * TMAX + tb] = cur1;
            }
        }
    }
}

// ---------------------------------------------------------------------------
// Kernel 2: flash-decode split. One block per (bh, split); 256 timesteps.
// 16 lanes per t-row, 2 float4 loads per lane in flight. Partials
// (m, l, unnormalized o[128]) written to workspace.
// ---------------------------------------------------------------------------
__global__ __launch_bounds__(256)
void attn_split_kernel(const float* __restrict__ q,
                       const float* __restrict__ knew,
                       const float* __restrict__ vnew,
                       const float* __restrict__ kc,
                       const float* __restrict__ vc,
                       const float* __restrict__ mask,
                       const int*   __restrict__ trace_T,
                       const int*   __restrict__ offp,
                       float* __restrict__ pm,
                       float* __restrict__ pl,
                       float* __restrict__ po) {
    const int off = *offp;
    const int T   = off + 1;
    const int TS  = (T + NSPLIT - 1) / NSPLIT;
    const int bh    = blockIdx.x >> 3;       // NSPLIT == 8
    const int split = blockIdx.x & (NSPLIT - 1);
    const int b = bh >> 5;                   // / HH
    const int h = bh & (HH - 1);
    const int t0 = split * TS;
    const int t1 = min(t0 + TS, T);

    __shared__ float sc[TS_MAX];
    __shared__ float red[8];
    __shared__ float oacc[4][DD];

    const int tid  = threadIdx.x;
    const int wave = tid >> 6;               // 0..3
    const int grp  = (tid >> 4) & 3;         // row group within wave
    const int l16  = tid & 15;
    const int d0   = l16 * 4;

    const float inv_scale = 0.08838834764831843f;  // 1/sqrt(128)

    const float* qp = q + (size_t)bh * DD;
    const float4 qf0 = *(const float4*)(qp + d0);
    const float4 qf1 = *(const float4*)(qp + d0 + 64);
    const int* tr = trace_T + b * TMAX;

    // ---- pass 1: scores ----
    float m_local = -3.4e38f;
    for (int t = t0 + wave * 4 + grp; t < t1; t += 16) {
        const float* kp;
        if (t < off) kp = kc + ((size_t)(t * BEAMS + tr[t]) * HH + h) * DD;
        else         kp = knew + (size_t)bh * DD;
        const float4 k0 = *(const float4*)(kp + d0);
        const float4 k1 = *(const float4*)(kp + d0 + 64);
        float s = qf0.x * k0.x + qf0.y * k0.y + qf0.z * k0.z + qf0.w * k0.w
                + qf1.x * k1.x + qf1.y * k1.y + qf1.z * k1.z + qf1.w * k1.w;
        #pragma unroll
        for (int o = 8; o > 0; o >>= 1) s += __shfl_xor(s, o, 16);
        s = s * inv_scale + mask[(size_t)b * T + t];
        if (l16 == 0) sc[t - t0] = s;
        m_local = fmaxf(m_local, s);
    }
    m_local = fmaxf(m_local, __shfl_xor(m_local, 16, 64));
    m_local = fmaxf(m_local, __shfl_xor(m_local, 32, 64));
    if ((tid & 63) == 0) red[wave] = m_local;
    __syncthreads();
    const float m = fmaxf(fmaxf(red[0], red[1]), fmaxf(red[2], red[3]));

    // ---- pass 2: exp + sum ----
    float sum_local = 0.f;
    const int n = t1 - t0;
    for (int i = tid; i < n; i += 256) {
        const float p = __expf(sc[i] - m);
        sc[i] = p;
        sum_local += p;
    }
    #pragma unroll
    for (int o = 32; o > 0; o >>= 1) sum_local += __shfl_xor(sum_local, o, 64);
    if ((tid & 63) == 0) red[4 + wave] = sum_local;
    __syncthreads();
    const float l = red[4] + red[5] + red[6] + red[7];

    // ---- pass 3: p * V (unnormalized) ----
    float a0x = 0.f, a0y = 0.f, a0z = 0.f, a0w = 0.f;
    float a1x = 0.f, a1y = 0.f, a1z = 0.f, a1w = 0.f;
    for (int t = t0 + wave * 4 + grp; t < t1; t += 16) {
        const float p = sc[t - t0];
        const float* vp;
        if (t < off) vp = vc + ((size_t)(t * BEAMS + tr[t]) * HH + h) * DD;
        else         vp = vnew + (size_t)bh * DD;
        const float4 v0 = *(const float4*)(vp + d0);
        const float4 v1 = *(const float4*)(vp + d0 + 64);
        a0x += p * v0.x; a0y += p * v0.y; a0z += p * v0.z; a0w += p * v0.w;
        a1x += p * v1.x; a1y += p * v1.y; a1z += p * v1.z; a1w += p * v1.w;
    }
    #pragma unroll
    for (int o = 16; o <= 32; o <<= 1) {
        a0x += __shfl_xor(a0x, o, 64); a0y += __shfl_xor(a0y, o, 64);
        a0z += __shfl_xor(a0z, o, 64); a0w += __shfl_xor(a0w, o, 64);
        a1x += __shfl_xor(a1x, o, 64); a1y += __shfl_xor(a1y, o, 64);
        a1z += __shfl_xor(a1z, o, 64); a1w += __shfl_xor(a1w, o, 64);
    }
    if (grp == 0) {
        oacc[wave][d0 + 0] = a0x; oacc[wave][d0 + 1] = a0y;
        oacc[wave][d0 + 2] = a0z; oacc[wave][d0 + 3] = a0w;
        oacc[wave][d0 + 64] = a1x; oacc[wave][d0 + 65] = a1y;
        oacc[wave][d0 + 66] = a1z; oacc[wave][d0 + 67] = a1w;
    }
    __syncthreads();
    if (tid < DD) {
        const float o = oacc[0][tid] + oacc[1][tid] + oacc[2][tid] + oacc[3][tid];
        po[(size_t)blockIdx.x * DD + tid] = o;
    }
    if (tid == 0) { pm[blockIdx.x] = m; pl[blockIdx.x] = l; }
}

// ---------------------------------------------------------------------------
// Kernel 3: merge the NSPLIT partials per (b,h).
// ---------------------------------------------------------------------------
__global__ __launch_bounds__(128)
void attn_reduce_kernel(const float* __restrict__ pm,
                        const float* __restrict__ pl,
                        const float* __restrict__ po,
                        float* __restrict__ out) {
    const int bh = blockIdx.x;
    const int d  = threadIdx.x;
    float m = -3.4e38f;
    #pragma unroll
    for (int s = 0; s < NSPLIT; ++s) m = fmaxf(m, pm[bh * NSPLIT + s]);
    float l = 0.f, o = 0.f;
    #pragma unroll
    for (int s = 0; s < NSPLIT; ++s) {
        const float w = __expf(pm[bh * NSPLIT + s] - m);
        l += pl[bh * NSPLIT + s] * w;
        o += po[(size_t)(bh * NSPLIT + s) * DD + d] * w;
    }
    out[(size_t)bh * DD + d] = o / l;
}

// ---------------------------------------------------------------------------
extern "C" void kernel_launch(void* const* d_in, const int* in_sizes, int n_in,
                              void* d_out, int out_size, void* d_ws, size_t ws_size,
                              hipStream_t stream) {
    const float* q    = (const float*)d_in[0];
    const float* knew = (const float*)d_in[1];
    const float* vnew = (const float*)d_in[2];
    const float* kc   = (const float*)d_in[3];
    const float* vc   = (const float*)d_in[4];
    const int*   bidx = (const int*)d_in[5];
    const float* mask = (const float*)d_in[6];
    const int*   offp = (const int*)d_in[7];

    // workspace layout
    int*   trace_T = (int*)d_ws;                               // 16*2048*4 = 128 KiB
    float* pm      = (float*)((char*)d_ws + BEAMS * TMAX * 4); // 4096 floats
    float* pl      = pm + BEAMS * HH * NSPLIT * 2;             // padded stride (safe)
    float* po      = pl + BEAMS * HH * NSPLIT * 2;             // 4096*128 floats = 2 MiB

    const int nbh = BEAMS * HH;   // 512

    hipLaunchKernelGGL(trace_kernel, dim3(1), dim3(1024), 0, stream,
                       bidx, offp, trace_T);
    hipLaunchKernelGGL(attn_split_kernel, dim3(nbh * NSPLIT), dim3(256), 0, stream,
                       q, knew, vnew, kc, vc, mask, trace_T, offp, pm, pl, po);
    hipLaunchKernelGGL(attn_reduce_kernel, dim3(nbh), dim3(128), 0, stream,
                       pm, pl, po, (float*)d_out);
}